// Round 3
// baseline (3018.885 us; speedup 1.0000x reference)
//
#include <hip/hip_runtime.h>

// Problem constants
#define BB 64       // batch
#define TT 512      // time steps
#define II 128      // input dim
#define HH 512      // hidden
#define CC 5        // out classes

// ---------------------------------------------------------------------------
// GEMM: out[m][n] = sum_k A[m][k] * W[n][k] + b1[n] + b2[n]   (baseline, kept)
// ---------------------------------------------------------------------------
__global__ __launch_bounds__(256) void gemm_bias_kernel(
    const float* __restrict__ A, const float* __restrict__ W,
    const float* __restrict__ b1, const float* __restrict__ b2,
    float* __restrict__ out, int K)
{
    __shared__ float As[16][132];
    __shared__ float Bs[16][132];
    const int tid = threadIdx.x;
    const int bm = blockIdx.x;
    const int bn = blockIdx.y;
    const int tx = tid & 15;
    const int ty = tid >> 4;
    const int lr = tid >> 2;
    const int lk = (tid & 3) << 2;

    const float* Ab = A + (size_t)bm * 128 * K;
    const float* Wb = W + (size_t)bn * 128 * K;

    float acc[8][8];
#pragma unroll
    for (int i = 0; i < 8; ++i)
#pragma unroll
        for (int j = 0; j < 8; ++j) acc[i][j] = 0.f;

    for (int k0 = 0; k0 < K; k0 += 16) {
        float4 a0 = *(const float4*)(Ab + (size_t)lr * K + k0 + lk);
        float4 a1 = *(const float4*)(Ab + (size_t)(lr + 64) * K + k0 + lk);
        float4 w0 = *(const float4*)(Wb + (size_t)lr * K + k0 + lk);
        float4 w1 = *(const float4*)(Wb + (size_t)(lr + 64) * K + k0 + lk);
        __syncthreads();
        As[lk + 0][lr] = a0.x; As[lk + 1][lr] = a0.y; As[lk + 2][lr] = a0.z; As[lk + 3][lr] = a0.w;
        As[lk + 0][lr + 64] = a1.x; As[lk + 1][lr + 64] = a1.y; As[lk + 2][lr + 64] = a1.z; As[lk + 3][lr + 64] = a1.w;
        Bs[lk + 0][lr] = w0.x; Bs[lk + 1][lr] = w0.y; Bs[lk + 2][lr] = w0.z; Bs[lk + 3][lr] = w0.w;
        Bs[lk + 0][lr + 64] = w1.x; Bs[lk + 1][lr + 64] = w1.y; Bs[lk + 2][lr + 64] = w1.z; Bs[lk + 3][lr + 64] = w1.w;
        __syncthreads();
#pragma unroll
        for (int k = 0; k < 16; ++k) {
            float4 av0 = *(const float4*)&As[k][ty * 8];
            float4 av1 = *(const float4*)&As[k][ty * 8 + 4];
            float4 bv0 = *(const float4*)&Bs[k][tx * 8];
            float4 bv1 = *(const float4*)&Bs[k][tx * 8 + 4];
            float a[8] = {av0.x, av0.y, av0.z, av0.w, av1.x, av1.y, av1.z, av1.w};
            float b[8] = {bv0.x, bv0.y, bv0.z, bv0.w, bv1.x, bv1.y, bv1.z, bv1.w};
#pragma unroll
            for (int i = 0; i < 8; ++i)
#pragma unroll
                for (int j = 0; j < 8; ++j)
                    acc[i][j] = fmaf(a[i], b[j], acc[i][j]);
        }
    }

    const int nb = bn * 128 + tx * 8;
    float bias[8];
#pragma unroll
    for (int j = 0; j < 8; ++j) bias[j] = b1[nb + j] + b2[nb + j];
#pragma unroll
    for (int i = 0; i < 8; ++i) {
        const size_t m = (size_t)bm * 128 + ty * 8 + i;
        float4 o0 = {acc[i][0] + bias[0], acc[i][1] + bias[1], acc[i][2] + bias[2], acc[i][3] + bias[3]};
        float4 o1 = {acc[i][4] + bias[4], acc[i][5] + bias[5], acc[i][6] + bias[6], acc[i][7] + bias[7]};
        *(float4*)(out + m * HH + nb) = o0;
        *(float4*)(out + m * HH + nb + 4) = o1;
    }
}

// ---------------------------------------------------------------------------
// DPP reduction helpers (VALU pipe; verified absmax==0 in round 2).
// ---------------------------------------------------------------------------
template <int CTRL>
__device__ __forceinline__ float dpp_add(float v) {
    const int t = __builtin_amdgcn_update_dpp(0, __float_as_int(v), CTRL, 0xf, 0xf, true);
    return v + __int_as_float(t);
}
__device__ __forceinline__ float reduce8(float v) {
    v = dpp_add<0xB1>(v);    // quad_perm xor 1
    v = dpp_add<0x4E>(v);    // quad_perm xor 2
    v = dpp_add<0x141>(v);   // row_half_mirror == xor 4 at this point
    return v;
}

// ---------------------------------------------------------------------------
// sc0 fast-path global ops: L1-bypass, L2-SERVED (vs agent-scope sc1 ops
// which bypass the XCD L2 and round-trip the Infinity Cache, ~600-700cy).
// Producer dual-stores (sc0 shadow + agent atomic, IDENTICAL payload);
// consumer polls 3x sc0 : 1x agent fallback. If partners share an XCD
// (blockIdx%8 round-robin puts all 8 slices of a group on one XCD), the
// sc0 store->load RT is the local L2 (~300-400cy). If placement differs,
// sc0 reads may be stale -> phase check fails -> the agent fallback
// guarantees forward progress. Correctness never depends on placement.
// ---------------------------------------------------------------------------
__device__ __forceinline__ unsigned long long load_sc0(const unsigned long long* p) {
    unsigned long long v;
    asm volatile("global_load_dwordx2 %0, %1, off sc0\n\ts_waitcnt vmcnt(0)"
                 : "=v"(v) : "v"(p) : "memory");
    return v;
}
__device__ __forceinline__ void store_sc0(unsigned long long* p, unsigned long long v) {
    asm volatile("global_store_dwordx2 %0, %1, off sc0"
                 :: "v"(p), "v"(v) : "memory");
}

// ---------------------------------------------------------------------------
// Recurrent scan (round-2 dataflow, unchanged except the publish/poll path).
// 256 blocks x 512 threads, blockIdx = s*32 + g.
//  lane = rgrp(lane>>3)*8 + khi(lane&7); wave wv
//  rows:     R = s*64 + rgrp*8 .. +8    (8 rows/lane, 64 weight VGPRs)
//  k-window: [(wv*8+khi)*8, +8)         -> wave wv consumes exactly chunk wv,
//  which is the chunk it polls itself => no cross-wave h gate.
// Cross-khi reduce: DPP. Cross-wave: parity LDS partials P + pflag; wave s
// (pub) gathers, adds xp (biases folded by gemm), relu, publishes packets.
// hbuf is PER-LAYER (3 x 512KB): stale L2 lines from layer k-1 (now possible
// because sc0 ops cache hbuf lines in L2) land in a region layer k never
// reads. Cross-iteration staleness is value-identical (deterministic replay).
// ---------------------------------------------------------------------------
__global__ __launch_bounds__(512)
__attribute__((amdgpu_waves_per_eu(2, 2)))
void scan_kernel(
    const float* __restrict__ xp, const float* __restrict__ Whh,
    float* __restrict__ y, unsigned long long* hbuf)
{
    __shared__ float lh[4][2][512];        // [buf][batch][h-elem] 16 KB
    __shared__ float P[2][8][64][2];       // [parity][wave][row][batch] 4 KB
    __shared__ int pflag[8];               // per-wave partial progress

    const int tid  = threadIdx.x;
    const int s    = blockIdx.x >> 5;      // slice: rows s*64..+64
    const int g    = blockIdx.x & 31;      // batches 2g, 2g+1
    const int lane = tid & 63;
    const int wv   = tid >> 6;
    const int rgrp = lane >> 3;            // 8-row group within slice
    const int khi  = lane & 7;             // k-subwindow within wave
    const int ks   = wv * 8 + khi;         // global k-window [ks*8, ks*8+8)

    // --- weights: rows s*64+rgrp*8+j (j=0..7), cols ks*8..+8 : 64 VGPRs ---
    const float* wb = Whh + (size_t)(s * 64 + rgrp * 8) * HH + ks * 8;
    float4 W0[8], W1[8];
#pragma unroll
    for (int j = 0; j < 8; ++j) {
        W0[j] = *(const float4*)(wb + (size_t)j * HH);
        W1[j] = *(const float4*)(wb + (size_t)j * HH + 4);
    }

    unsigned long long* gbase = hbuf + (size_t)g * 2048;  // [slot 0..3][512]
    const int gb0 = g * 2, gb1 = g * 2 + 1;
    const bool ispub = (wv == s);
    const int prow = s * 64 + lane;        // pub lane's global row

    lh[0][0][tid] = 0.f;
    lh[0][1][tid] = 0.f;
    if (tid < 8) pflag[tid] = 0;

    float xq0 = 0.f, xq1 = 0.f;
    if (ispub) {
        xq0 = xp[(size_t)gb0 * TT * HH + prow];
        xq1 = xp[(size_t)gb1 * TT * HH + prow];
    }
    __syncthreads();   // one-time: LDS init visible

    for (int t = 0; t < TT; ++t) {
        const int bi = t & 3;
        const int par = t & 1;
        const int q = t + 1;

        // --- (1) window read (4 x ds_read_b128) ---
        const float* h0p = &lh[bi][0][wv * 64 + khi * 8];
        const float* h1p = &lh[bi][1][wv * 64 + khi * 8];
        const float4 ha0 = *(const float4*)(h0p);
        const float4 ha1 = *(const float4*)(h0p + 4);
        const float4 hb0 = *(const float4*)(h1p);
        const float4 hb1 = *(const float4*)(h1p + 4);

        // --- (2) 128 FMA: 8 rows x 8 k x 2 batches ---
        float pa[8], pb[8];
#pragma unroll
        for (int j = 0; j < 8; ++j) {
            float u = W0[j].x * ha0.x;
            u = fmaf(W0[j].y, ha0.y, u); u = fmaf(W0[j].z, ha0.z, u); u = fmaf(W0[j].w, ha0.w, u);
            u = fmaf(W1[j].x, ha1.x, u); u = fmaf(W1[j].y, ha1.y, u);
            u = fmaf(W1[j].z, ha1.z, u); u = fmaf(W1[j].w, ha1.w, u);
            pa[j] = u;
            float v = W0[j].x * hb0.x;
            v = fmaf(W0[j].y, hb0.y, v); v = fmaf(W0[j].z, hb0.z, v); v = fmaf(W0[j].w, hb0.w, v);
            v = fmaf(W1[j].x, hb1.x, v); v = fmaf(W1[j].y, hb1.y, v);
            v = fmaf(W1[j].z, hb1.z, v); v = fmaf(W1[j].w, hb1.w, v);
            pb[j] = v;
        }

        // --- (3) DPP reduce over the 8 khi lanes ---
#pragma unroll
        for (int j = 0; j < 8; ++j) {
            pa[j] = reduce8(pa[j]);
            pb[j] = reduce8(pb[j]);
        }

        // --- (4) write per-wave partials + flag ---
        if (khi == 0) {
            float* pw = &P[par][wv][rgrp * 8][0];
            float4 o0 = {pa[0], pb[0], pa[1], pb[1]};
            float4 o1 = {pa[2], pb[2], pa[3], pb[3]};
            float4 o2 = {pa[4], pb[4], pa[5], pb[5]};
            float4 o3 = {pa[6], pb[6], pa[7], pb[7]};
            *(float4*)(pw + 0)  = o0;
            *(float4*)(pw + 4)  = o1;
            *(float4*)(pw + 8)  = o2;
            *(float4*)(pw + 12) = o3;
        }
        __threadfence_block();   // release: P visible before flag
        if (lane == 0)
            __hip_atomic_store(&pflag[wv], q, __ATOMIC_RELAXED,
                               __HIP_MEMORY_SCOPE_WORKGROUP);

        if (ispub) {
            // --- (5) gather: spin 8 flags, sum 8 wave-partials + xp, relu ---
            for (;;) {
                int m = __hip_atomic_load(&pflag[0], __ATOMIC_RELAXED,
                                          __HIP_MEMORY_SCOPE_WORKGROUP);
#pragma unroll
                for (int c = 1; c < 8; ++c) {
                    int wc = __hip_atomic_load(&pflag[c], __ATOMIC_RELAXED,
                                               __HIP_MEMORY_SCOPE_WORKGROUP);
                    m = (wc < m) ? wc : m;
                }
                if (m >= q) break;
            }
            __threadfence_block();   // acquire

            float s0 = xq0, s1 = xq1;   // xp already includes b_ih+b_hh
#pragma unroll
            for (int w = 0; w < 8; ++w) {
                const float2 pr = *(const float2*)&P[par][w][lane][0];
                s0 += pr.x;
                s1 += pr.y;
            }
            const float hn0 = fmaxf(s0, 0.f);
            const float hn1 = fmaxf(s1, 0.f);

            if (q < TT) {
                unsigned long long* slotp = gbase + (q & 3) * 512;
                const unsigned int phase = 1u ^ (((unsigned)(q - 1) >> 2) & 1u);
                const unsigned long long pkt =
                    (unsigned long long)(__float_as_uint(hn0) | (phase << 31)) |
                    ((unsigned long long)(__float_as_uint(hn1) | (phase << 31)) << 32);
                // dual-store publish: sc0 shadow (same-XCD L2 fast path) +
                // agent atomic (coherence-point guarantee). Same payload =>
                // store order irrelevant; all prior protocol proofs carry.
                store_sc0(slotp + prow, pkt);
                __hip_atomic_store(slotp + prow, pkt,
                                   __ATOMIC_RELAXED, __HIP_MEMORY_SCOPE_AGENT);
                lh[q & 3][0][prow] = hn0;
                lh[q & 3][1][prow] = hn1;
                xq0 = xp[((size_t)gb0 * TT + q) * HH + prow];
                xq1 = xp[((size_t)gb1 * TT + q) * HH + prow];
            }
            y[((size_t)gb0 * TT + t) * HH + prow] = hn0;
            y[((size_t)gb1 * TT + t) * HH + prow] = hn1;
        } else if (q < TT) {
            // --- (6) hybrid poll of own chunk wv (row tid) ---
            const unsigned long long* pp = gbase + (q & 3) * 512 + tid;
            const unsigned int phase = 1u ^ (((unsigned)(q - 1) >> 2) & 1u);
            unsigned long long u;
            int it = 0;
            for (;;) {
                if ((it++ & 3) == 0)
                    u = __hip_atomic_load(pp, __ATOMIC_RELAXED,
                                          __HIP_MEMORY_SCOPE_AGENT);
                else
                    u = load_sc0(pp);
                if ((((unsigned int)(u >> 31) & 1u) == phase) &&
                    ((unsigned int)(u >> 63) == phase)) break;
            }
            lh[q & 3][0][tid] = __uint_as_float((unsigned int)u & 0x7fffffffu);
            lh[q & 3][1][tid] = __uint_as_float((unsigned int)(u >> 32) & 0x7fffffffu);
        }
    }
}

// ---------------------------------------------------------------------------
// Head: out[b][c] = sum_h y[b][T-1][h] * W_out[c][h] + b_out[c]   (baseline)
// ---------------------------------------------------------------------------
__global__ __launch_bounds__(64) void head_kernel(
    const float* __restrict__ y2, const float* __restrict__ Wout,
    const float* __restrict__ bout, float* __restrict__ out)
{
    const int bc = blockIdx.x;
    const int b = bc / CC, c = bc % CC;
    const int lane = threadIdx.x;
    const float* yrow = y2 + ((size_t)b * TT + (TT - 1)) * HH;
    const float* wrow = Wout + (size_t)c * HH;
    float s = 0.f;
#pragma unroll
    for (int i = 0; i < HH / 64; ++i)
        s = fmaf(yrow[lane + 64 * i], wrow[lane + 64 * i], s);
#pragma unroll
    for (int off = 32; off > 0; off >>= 1) s += __shfl_down(s, off);
    if (lane == 0) out[bc] = s + bout[c];
}

// ---------------------------------------------------------------------------
extern "C" void kernel_launch(void* const* d_in, const int* in_sizes, int n_in,
                              void* d_out, int out_size, void* d_ws, size_t ws_size,
                              hipStream_t stream)
{
    (void)in_sizes; (void)n_in; (void)out_size; (void)ws_size;
    const float* x = (const float*)d_in[0];
    const float* W_ih[3] = {(const float*)d_in[1], (const float*)d_in[5], (const float*)d_in[9]};
    const float* W_hh[3] = {(const float*)d_in[2], (const float*)d_in[6], (const float*)d_in[10]};
    const float* b_ih[3] = {(const float*)d_in[3], (const float*)d_in[7], (const float*)d_in[11]};
    const float* b_hh[3] = {(const float*)d_in[4], (const float*)d_in[8], (const float*)d_in[12]};
    const float* W_out = (const float*)d_in[13];
    const float* b_out = (const float*)d_in[14];
    float* out = (float*)d_out;

    // workspace layout (floats): Y (64MB), XP (64MB), hbuf[3] (3 x 512KB).
    // Per-layer hbuf regions: stale-L2-line isolation across layers (see scan).
    float* ws   = (float*)d_ws;
    float* Y    = ws;                        // B*T*H
    float* XP   = ws + (size_t)BB * TT * HH; // B*T*H
    unsigned long long* hbuf0 = (unsigned long long*)(XP + (size_t)BB * TT * HH);
    const size_t hbuf_words = (size_t)32 * 4 * 512;   // 64K packets / layer
    unsigned long long* hb[3] = {hbuf0, hbuf0 + hbuf_words, hbuf0 + 2 * hbuf_words};

    (void)hipMemsetAsync(hbuf0, 0, 3 * hbuf_words * sizeof(unsigned long long), stream);

    const dim3 ggrid(256, 4, 1);

    // layer 0
    gemm_bias_kernel<<<ggrid, 256, 0, stream>>>(x, W_ih[0], b_ih[0], b_hh[0], XP, II);
    scan_kernel<<<256, 512, 0, stream>>>(XP, W_hh[0], Y, hb[0]);
    // layer 1
    gemm_bias_kernel<<<ggrid, 256, 0, stream>>>(Y, W_ih[1], b_ih[1], b_hh[1], XP, HH);
    scan_kernel<<<256, 512, 0, stream>>>(XP, W_hh[1], Y, hb[1]);
    // layer 2
    gemm_bias_kernel<<<ggrid, 256, 0, stream>>>(Y, W_ih[2], b_ih[2], b_hh[2], XP, HH);
    scan_kernel<<<256, 512, 0, stream>>>(XP, W_hh[2], Y, hb[2]);
    // head
    head_kernel<<<BB * CC, 64, 0, stream>>>(Y, W_out, b_out, out);
}